// Round 1
// baseline (2620.807 us; speedup 1.0000x reference)
//
#include <hip/hip_runtime.h>

#define THREADS 512
#define TB 128
#define H 256
#define DIN 60
#define DOUT 360
#define CS_STRIDE 62    // floats per centres row in LDS (8B-aligned, conflict-free)
#define W2_STRIDE 40    // shorts per w2s row (32 data + 8 pad -> bank-spread)
#define NT 23           // 23 * 16 = 368 padded output columns

typedef __attribute__((ext_vector_type(8))) short short8;
typedef __attribute__((ext_vector_type(4))) float f32x4;
typedef __attribute__((ext_vector_type(2))) float f32x2;

__device__ __forceinline__ short bf16_bits(float f) {
    union { float f; unsigned u; } v; v.f = f;
    unsigned r = (v.u + 0x7FFFu + ((v.u >> 16) & 1u)) >> 16;   // RNE
    return (short)(unsigned short)r;
}

__global__ __launch_bounds__(THREADS, 2)
void rbf_fused(const float* __restrict__ x, const float* __restrict__ centres,
               const float* __restrict__ sigmas, const float* __restrict__ W2,
               float* __restrict__ out)
{
    __shared__ float cs[H * CS_STRIDE];     // 63488 B
    __shared__ float nsig2[H];              // 1024 B
    __shared__ float c2[H];                 // 1024 B
    __shared__ short w2s[368 * W2_STRIDE];  // 29440 B   (total ~93 KB LDS)

    const int tid = threadIdx.x;
    const int w   = tid >> 6;         // wave 0..7 -> 16-row M tile
    const int l15 = tid & 15;
    const int g   = (tid >> 4) & 3;   // lane quad-group
    const int b0  = blockIdx.x * TB;

    // ---- stage centres into LDS (float2 granularity; 15*512 = 7680 = 256*30) ----
    #pragma unroll
    for (int it = 0; it < 15; ++it) {
        int i2  = tid + it * THREADS;
        int row = i2 / 30;
        int c   = (i2 % 30) * 2;
        f32x2 v = *(const f32x2*)(centres + row * DIN + c);
        *(f32x2*)(cs + row * CS_STRIDE + c) = v;
    }
    if (tid < H) { float s = sigmas[tid]; nsig2[tid] = -s * s; }
    __syncthreads();
    if (tid < H) {  // centre norms
        const float* r = cs + tid * CS_STRIDE;
        float s = 0.f;
        #pragma unroll
        for (int d = 0; d < DIN; ++d) s = fmaf(r[d], r[d], s);
        c2[tid] = s;
    }

    // ---- per-lane x row into registers (lane's A-frag row m = l15) ----
    const int brow = b0 + w * 16 + l15;
    const float* xr = x + brow * DIN;
    f32x2 xv2[30];
    #pragma unroll
    for (int i = 0; i < 15; ++i) {
        f32x4 t = *(const f32x4*)(xr + 4 * i);      // 16B-aligned (240B rows)
        f32x2 lo; lo[0] = t[0]; lo[1] = t[1];
        f32x2 hi; hi[0] = t[2]; hi[1] = t[3];
        xv2[2 * i] = lo; xv2[2 * i + 1] = hi;
    }
    f32x2 s2; s2[0] = 0.f; s2[1] = 0.f;
    #pragma unroll
    for (int i = 0; i < 30; ++i) s2 += xv2[i] * xv2[i];
    const float x2 = s2[0] + s2[1];

    f32x4 acc[NT];
    #pragma unroll
    for (int nt = 0; nt < NT; ++nt) acc[nt] = (f32x4){0.f, 0.f, 0.f, 0.f};

    __syncthreads();   // c2 ready

    for (int kt = 0; kt < 8; ++kt) {
        __syncthreads();   // previous k-slice MFMA reads of w2s are done

        // -- issue global loads of the W2 k-slice early (permuted rows) --
        f32x4 sra[3], srb[3];
        int sop[3], sseg[3]; bool sval[3];
        #pragma unroll
        for (int it = 0; it < 3; ++it) {
            int idx = tid + it * THREADS;         // 368 rows * 4 segs = 1472 tasks
            sval[it] = (idx < 368 * 4);
            int op = idx >> 2, seg = idx & 3;
            sop[it] = op; sseg[it] = seg;
            if (sval[it] && op < DOUT) {
                // output column permutation folded into W2 row order:
                // final col c=op: r=c/12=f*3+k, j=c%12 -> source row o=f*36+j*3+k
                int rr = op / 12, jj = op % 12;
                int f = rr / 3, kk = rr % 3;
                int o = f * 36 + jj * 3 + kk;
                const float* p = W2 + o * H + kt * 32 + seg * 8;
                sra[it] = *(const f32x4*)p;
                srb[it] = *(const f32x4*)(p + 4);
            } else {
                sra[it] = (f32x4){0,0,0,0};
                srb[it] = (f32x4){0,0,0,0};
            }
        }

        // -- phi for this k-tile straight into the A-fragment (covers load latency) --
        short8 af;
        #pragma unroll
        for (int j = 0; j < 8; ++j) {
            int h = kt * 32 + g * 8 + j;         // A-frag: m=l15, k=g*8+j
            const float* crow = cs + h * CS_STRIDE;
            f32x2 pA; pA[0] = 0.f; pA[1] = 0.f;
            f32x2 pB; pB[0] = 0.f; pB[1] = 0.f;
            #pragma unroll
            for (int dp = 0; dp < 30; ++dp) {
                f32x2 cv = *(const f32x2*)(crow + 2 * dp);   // 16-lane broadcast
                if (dp & 1) pB += xv2[dp] * cv;
                else        pA += xv2[dp] * cv;
            }
            float xc = (pA[0] + pB[0]) + (pA[1] + pB[1]);
            float d2 = fmaxf(x2 + c2[h] - 2.f * xc, 0.f);
            float p  = __expf(nsig2[h] * d2);
            af[j] = bf16_bits(p);
        }

        // -- write staged W2 slice to LDS as bf16 --
        #pragma unroll
        for (int it = 0; it < 3; ++it) {
            if (sval[it]) {
                short8 pk;
                pk[0] = bf16_bits(sra[it][0]); pk[1] = bf16_bits(sra[it][1]);
                pk[2] = bf16_bits(sra[it][2]); pk[3] = bf16_bits(sra[it][3]);
                pk[4] = bf16_bits(srb[it][0]); pk[5] = bf16_bits(srb[it][1]);
                pk[6] = bf16_bits(srb[it][2]); pk[7] = bf16_bits(srb[it][3]);
                *(short8*)(w2s + sop[it] * W2_STRIDE + sseg[it] * 8) = pk;
            }
        }
        __syncthreads();

        // -- MFMA across all N tiles; acc stays resident --
        #pragma unroll
        for (int nt = 0; nt < NT; ++nt) {
            short8 bf = *(const short8*)(w2s + (nt * 16 + l15) * W2_STRIDE + g * 8);
            acc[nt] = __builtin_amdgcn_mfma_f32_16x16x32_bf16(af, bf, acc[nt], 0, 0, 0);
        }
    }

    // ---- store (columns already in final permuted order) ----
    const int orow = b0 + w * 16 + g * 4;   // D: col=l15, row=g*4+r
    #pragma unroll
    for (int nt = 0; nt < NT; ++nt) {
        int col = nt * 16 + l15;
        if (col < DOUT) {
            #pragma unroll
            for (int r = 0; r < 4; ++r)
                out[(orow + r) * DOUT + col] = acc[nt][r];
        }
    }
}

extern "C" void kernel_launch(void* const* d_in, const int* in_sizes, int n_in,
                              void* d_out, int out_size, void* d_ws, size_t ws_size,
                              hipStream_t stream) {
    const float* x       = (const float*)d_in[0];
    const float* centres = (const float*)d_in[1];
    const float* sigmas  = (const float*)d_in[2];
    const float* W2      = (const float*)d_in[3];
    float* out = (float*)d_out;
    const int Brows = in_sizes[0] / DIN;       // 131072
    dim3 grid(Brows / TB);                     // 1024
    rbf_fused<<<grid, THREADS, 0, stream>>>(x, centres, sigmas, W2, out);
}

// Round 2
// 79.754 us; speedup vs baseline: 32.8613x; 32.8613x over previous
//
#include <hip/hip_runtime.h>

#define THREADS 512
#define TB 128          // rows per block (8 waves x 16)
#define DIN 60
#define HN 256
#define DOUT 360
#define NT2 23          // GEMM2 N tiles (23*16 = 368 padded cols)
#define KT2 8           // GEMM2 K tiles (256/32)

typedef __attribute__((ext_vector_type(8))) short short8;
typedef __attribute__((ext_vector_type(4))) float f32x4;

// d_ws layout (bytes); total 231424 B
#define WS_CBF   0            // 2048 tasks * 16 B = 32768   (centres bf16, swizzled)
#define WS_C2    32768        // 256 * 4
#define WS_NS2   33792        // 256 * 4  (-sigma^2 * log2(e))
#define WS_W2    34816        // 8 kt * 1536 tasks * 16 B = 196608 (W2 bf16, permuted+swizzled)

__device__ __forceinline__ short bf16_bits(float f) {
    union { float f; unsigned u; } v; v.f = f;
    unsigned r = (v.u + 0x7FFFu + ((v.u >> 16) & 1u)) >> 16;   // RNE
    return (short)(unsigned short)r;
}

__device__ __forceinline__ void gload16(const void* g, void* lds) {
    // direct global->LDS DMA, 16B per lane (dest = wave-uniform base + lane*16)
    __builtin_amdgcn_global_load_lds(
        (const __attribute__((address_space(1))) unsigned int*)(uintptr_t)g,
        (__attribute__((address_space(3))) unsigned int*)(unsigned int)(uintptr_t)lds,
        16, 0, 0);
}

// ---------------- prep: convert/permute/swizzle constants into ws ----------------
__global__ void prep(const float* __restrict__ centres, const float* __restrict__ sigmas,
                     const float* __restrict__ W2, short* __restrict__ ws)
{
    int t = blockIdx.x * 256 + threadIdx.x;
    if (t < 12288) {
        // W2 k-slices: layout [kt][row 0..383][phys chunk p 0..3] of short8
        int kt = t / 1536, rem = t % 1536;
        int row = rem >> 2, p = rem & 3;
        int c = p ^ ((row >> 1) & 3);            // logical k-chunk stored at p
        short8 v = {0,0,0,0,0,0,0,0};
        if (row < DOUT) {
            // fold output column permutation: final col 'row' <- source row o
            int rr = row / 12, jj = row % 12;
            int f = rr / 3, kk = rr % 3;
            int o = f * 36 + jj * 3 + kk;
            const float* src = W2 + o * HN + kt * 32 + c * 8;
            #pragma unroll
            for (int i = 0; i < 8; ++i) v[i] = bf16_bits(src[i]);
        }
        *(short8*)(ws + (WS_W2 / 2) + t * 8) = v;
    } else if (t < 14336) {
        // centres bf16: [row 0..255][phys chunk p 0..7], k padded 60->64 with 0
        int j = t - 12288;
        int row = j >> 3, p = j & 7;
        int c = p ^ (row & 7);
        short8 v = {0,0,0,0,0,0,0,0};
        #pragma unroll
        for (int i = 0; i < 8; ++i) {
            int k = c * 8 + i;
            if (k < DIN) v[i] = bf16_bits(centres[row * DIN + k]);
        }
        *(short8*)(ws + (WS_CBF / 2) + j * 8) = v;
    } else if (t < 14592) {
        int i = t - 14336;
        const float* cr = centres + i * DIN;
        float s = 0.f;
        #pragma unroll
        for (int d = 0; d < DIN; ++d) s = fmaf(cr[d], cr[d], s);
        ((float*)ws)[WS_C2 / 4 + i] = s;
        float sg = sigmas[i];
        ((float*)ws)[WS_NS2 / 4 + i] = -sg * sg * 1.44269504088896340736f;
    }
}

// ---------------- main fused kernel ----------------
__global__ __launch_bounds__(THREADS, 2)
void rbf_main(const float* __restrict__ x, const short* __restrict__ ws,
              float* __restrict__ out)
{
    __shared__ short8 cbf[2048];                                   // 32 KB
    __shared__ short8 w2s[2][1536];                                // 48 KB (double buffer)
    __shared__ __attribute__((aligned(16))) short phiL[32768];     // 64 KB: 8 waves x [16][256]
    __shared__ float  x2s[TB];
    __shared__ float  c2s[HN];
    __shared__ float  ns2s[HN];

    const int tid  = threadIdx.x;
    const int w    = tid >> 6;
    const int lane = tid & 63;
    const int l15  = lane & 15;
    const int g    = lane >> 4;
    const int b0   = blockIdx.x * TB;

    // ---- prologue staging (async) ----
    #pragma unroll
    for (int it = 0; it < 4; ++it)
        gload16(ws + (WS_CBF / 2) + (it * THREADS + tid) * 8, &cbf[it * THREADS + tid]);
    #pragma unroll
    for (int it = 0; it < 3; ++it)       // W2 slice kt=0 -> buffer 0
        gload16(ws + (WS_W2 / 2) + (it * THREADS + tid) * 8, &w2s[0][it * THREADS + tid]);
    if (tid < HN)            c2s[tid]       = ((const float*)ws)[WS_C2 / 4 + tid];
    else if (tid < 2 * HN)   ns2s[tid - HN] = ((const float*)ws)[WS_NS2 / 4 + tid - HN];

    // ---- per-lane x fragment (row = l15, k = kt*32 + g*8 + j) + row norm ----
    const float* xr = x + (size_t)(b0 + w * 16 + l15) * DIN;
    f32x4 xa[2][2];
    #pragma unroll
    for (int kt = 0; kt < 2; ++kt) {
        int k0 = kt * 32 + g * 8;
        xa[kt][0] = *(const f32x4*)(xr + k0);
        if (k0 + 4 < DIN) xa[kt][1] = *(const f32x4*)(xr + k0 + 4);
        else              xa[kt][1] = (f32x4){0.f, 0.f, 0.f, 0.f};
    }
    float p2 = 0.f;
    #pragma unroll
    for (int kt = 0; kt < 2; ++kt)
        #pragma unroll
        for (int h = 0; h < 2; ++h)
            #pragma unroll
            for (int i = 0; i < 4; ++i) p2 = fmaf(xa[kt][h][i], xa[kt][h][i], p2);
    p2 += __shfl_xor(p2, 16);          // the 4 g-lanes of a row partition k
    p2 += __shfl_xor(p2, 32);
    x2s[w * 16 + l15] = p2;            // 4 lanes write identical value: benign

    short8 af[2];
    #pragma unroll
    for (int kt = 0; kt < 2; ++kt) {
        short8 a;
        #pragma unroll
        for (int i = 0; i < 4; ++i) a[i]     = bf16_bits(xa[kt][0][i]);
        #pragma unroll
        for (int i = 0; i < 4; ++i) a[4 + i] = bf16_bits(xa[kt][1][i]);
        af[kt] = a;
    }

    __syncthreads();   // cbf, w2s[0], c2s/ns2s, x2s all ready

    // ---- GEMM1: S = x . centres^T  (16 N-tiles x 2 K-steps) ----
    f32x4 acc1[16];
    #pragma unroll
    for (int nt = 0; nt < 16; ++nt) acc1[nt] = (f32x4){0.f, 0.f, 0.f, 0.f};
    #pragma unroll
    for (int nt = 0; nt < 16; ++nt) {
        int row = nt * 16 + l15;
        #pragma unroll
        for (int kt = 0; kt < 2; ++kt) {
            short8 bf = cbf[row * 8 + ((kt * 4 + g) ^ (row & 7))];
            acc1[nt] = __builtin_amdgcn_mfma_f32_16x16x32_bf16(af[kt], bf, acc1[nt], 0, 0, 0);
        }
    }

    // ---- phi = exp2(ns2l*(x2 + c2 - 2S)) -> per-wave LDS transpose (bf16) ----
    float xq[4];
    #pragma unroll
    for (int r = 0; r < 4; ++r) xq[r] = x2s[w * 16 + g * 4 + r];
    short* phiW = phiL + w * 4096;
    #pragma unroll
    for (int nt = 0; nt < 16; ++nt) {
        int hcol = nt * 16 + l15;
        float c2v = c2s[hcol];
        float nsv = ns2s[hcol];
        int cW = nt * 2 + (l15 >> 3);
        int ce = l15 & 7;
        #pragma unroll
        for (int r = 0; r < 4; ++r) {
            float d2 = fmaxf(xq[r] + c2v - 2.f * acc1[nt][r], 0.f);
            float ph = exp2f(nsv * d2);
            int row = g * 4 + r;
            phiW[row * 256 + ((cW ^ (row & 15)) * 8) + ce] = bf16_bits(ph);
        }
    }
    // phiL region is written and read by the SAME wave only -> no barrier needed.

    // ---- GEMM2: out = phi . W2^T  (23 N-tiles x 8 K-steps, dbuf staging) ----
    f32x4 acc2[NT2];
    #pragma unroll
    for (int nt = 0; nt < NT2; ++nt) acc2[nt] = (f32x4){0.f, 0.f, 0.f, 0.f};

    for (int kt = 0; kt < KT2; ++kt) {
        const int buf = kt & 1;
        if (kt < KT2 - 1) {   // prefetch next k-slice into the other buffer
            #pragma unroll
            for (int it = 0; it < 3; ++it)
                gload16(ws + (WS_W2 / 2) + ((kt + 1) * 1536 + it * THREADS + tid) * 8,
                        &w2s[buf ^ 1][it * THREADS + tid]);
        }
        short8 af2 = *(const short8*)(phiW + l15 * 256 + ((kt * 4 + g) ^ l15) * 8);
        #pragma unroll
        for (int nt = 0; nt < NT2; ++nt) {
            int row = nt * 16 + l15;
            short8 bf = w2s[buf][row * 4 + (g ^ ((row >> 1) & 3))];
            acc2[nt] = __builtin_amdgcn_mfma_f32_16x16x32_bf16(af2, bf, acc2[nt], 0, 0, 0);
        }
        __syncthreads();   // drains vmcnt(0): prefetch landed; separates buffer reuse
    }

    // ---- store (columns already in final permuted order) ----
    const int orow = b0 + w * 16 + g * 4;
    #pragma unroll
    for (int nt = 0; nt < NT2; ++nt) {
        int col = nt * 16 + l15;
        if (col < DOUT) {
            #pragma unroll
            for (int r = 0; r < 4; ++r)
                out[(size_t)(orow + r) * DOUT + col] = acc2[nt][r];
        }
    }
}

extern "C" void kernel_launch(void* const* d_in, const int* in_sizes, int n_in,
                              void* d_out, int out_size, void* d_ws, size_t ws_size,
                              hipStream_t stream) {
    const float* x       = (const float*)d_in[0];
    const float* centres = (const float*)d_in[1];
    const float* sigmas  = (const float*)d_in[2];
    const float* W2      = (const float*)d_in[3];
    float* out = (float*)d_out;
    short* ws  = (short*)d_ws;                  // needs 231424 B
    const int Brows = in_sizes[0] / DIN;        // 131072

    prep<<<dim3(57), dim3(256), 0, stream>>>(centres, sigmas, W2, ws);
    rbf_main<<<dim3(Brows / TB), dim3(THREADS), 0, stream>>>(x, ws, out);
}